// Round 1
// baseline (707.382 us; speedup 1.0000x reference)
//
#include <hip/hip_runtime.h>

#define NTHREADS 256
#define TILE 64
#define HALO 12
#define REGN 88      // TILE + 2*HALO
#define STR  92      // padded LDS row stride (floats), multiple of 4
#define NITER 11     // 1 initial + NUM_ITER=10
#define IMG  1024
#define KROWS 9      // rows per pass-1 job (9*92 % 32 != 0 -> dodge bank alias)

__device__ __forceinline__ void rowmin4(const float* __restrict__ row,
                                        int x0, int xl, int xr, float m[4]) {
    float4 v = *(const float4*)(row + x0);
    float l = row[xl];
    float r = row[xr];
    m[0] = fminf(fminf(l,   v.x), v.y);
    m[1] = fminf(fminf(v.x, v.y), v.z);
    m[2] = fminf(fminf(v.y, v.z), v.w);
    m[3] = fminf(fminf(v.z, v.w), r);
}

__device__ __forceinline__ void rowmax4(const float* __restrict__ row,
                                        int x0, int xl, int xr, float m[4]) {
    float4 v = *(const float4*)(row + x0);
    float l = row[xl];
    float r = row[xr];
    m[0] = fmaxf(fmaxf(l,   v.x), v.y);
    m[1] = fmaxf(fmaxf(v.x, v.y), v.z);
    m[2] = fmaxf(fmaxf(v.y, v.z), v.w);
    m[3] = fmaxf(fmaxf(v.z, v.w), r);
}

// ws[0] = sum(skel_pred * target), ws[1] = sum(skel_pred)
// ws[2] = sum(skel_target * sigmoid(pred)), ws[3] = sum(skel_target)
__global__ __launch_bounds__(NTHREADS, 2)
void cldice_main(const float* __restrict__ pred,
                 const float* __restrict__ target,
                 double* __restrict__ ws)
{
    __shared__ __align__(16) float buf[2][REGN][STR];
    __shared__ double red[8];

    const int tid = threadIdx.x;
    const int tx = blockIdx.x, ty = blockIdx.y;
    const int b = blockIdx.z >> 1, phase = blockIdx.z & 1;
    const int oy = ty * TILE - HALO;
    const int ox = tx * TILE - HALO;
    const size_t base = (size_t)b * (size_t)(IMG * IMG);
    const float* __restrict__ src = phase ? target : pred;  // img source
    const float* __restrict__ oth = phase ? pred : target;  // multiplied tensor

    const float PINF =  __builtin_huge_valf();
    const float NINF = -__builtin_huge_valf();

    // image-OOB bounds of the local region (for border blocks only)
    const int ylo = max(0, -oy), yhi = min(REGN, IMG - oy);
    const int xlo = max(0, -ox), xhi = min(REGN, IMG - ox);
    const bool border = (ylo > 0) || (yhi < REGN) || (xlo > 0) || (xhi < REGN);

    // ---- load e = buf[0]: img (sigmoid(pred) for phase 0, raw target for 1)
    for (int i = tid; i < REGN * REGN; i += NTHREADS) {
        int ly = i / REGN, lx = i - ly * REGN;
        int gy = oy + ly, gx = ox + lx;
        float v = PINF;   // +inf: identity for the first (min) pass
        if ((unsigned)gy < (unsigned)IMG && (unsigned)gx < (unsigned)IMG) {
            float rr = src[base + (size_t)gy * IMG + gx];
            v = phase ? rr : 1.0f / (1.0f + __expf(-rr));
        }
        buf[0][ly][lx] = v;
    }
    __syncthreads();

    // each thread owns a fixed 4x4 output patch; skel lives in registers
    float skel[4][4];
    const int rg = (tid >> 4) << 2;   // 0..60 (output row base in tile)
    const int cc = (tid & 15) << 2;   // 0..60 (output col base in tile)
    const int ly0 = HALO + rg;
    const int lx0 = HALO + cc;

    int cur = 0;
    for (int it = 0; it < NITER; ++it) {
        const int R = HALO - it;      // current valid radius of e
        const int nxt = cur ^ 1;

        // ---- pass 1: er(buf[nxt]) = erode(e=buf[cur]) at radius R-1
        {
            const int row0   = HALO - (R - 1);          // 13-R
            const int rowEnd = row0 + TILE + 2 * (R - 1);
            const int c0  = row0 >> 2;
            const int c1  = (rowEnd - 1) >> 2;
            const int nch = c1 - c0 + 1;
            const int nrb = (rowEnd - row0 + KROWS - 1) / KROWS;
            for (int job = tid; job < nch * nrb; job += NTHREADS) {
                const int rb = job / nch;
                const int c  = c0 + (job - rb * nch);
                const int x0 = c << 2;
                const int xl = max(x0 - 1, 0);          // clamped reads only
                const int xr = min(x0 + 4, REGN - 1);   // affect unused outputs
                const int r0 = row0 + rb * KROWS;
                const int r1 = min(r0 + KROWS, rowEnd);
                float a[4], bb[4], c2[4];
                rowmin4(buf[cur][r0 - 1], x0, xl, xr, a);
                rowmin4(buf[cur][r0],     x0, xl, xr, bb);
                for (int r = r0; r < r1; ++r) {
                    rowmin4(buf[cur][r + 1], x0, xl, xr, c2);
                    float4 er;
                    er.x = fminf(fminf(a[0], bb[0]), c2[0]);
                    er.y = fminf(fminf(a[1], bb[1]), c2[1]);
                    er.z = fminf(fminf(a[2], bb[2]), c2[2]);
                    er.w = fminf(fminf(a[3], bb[3]), c2[3]);
                    *(float4*)&buf[nxt][r][x0] = er;
#pragma unroll
                    for (int j = 0; j < 4; ++j) { a[j] = bb[j]; bb[j] = c2[j]; }
                }
            }
        }
        __syncthreads();

        // border blocks: er at image-OOB coords must be -inf for the max pass
        if (border) {
            for (int i = tid; i < REGN * REGN; i += NTHREADS) {
                int ly = i / REGN, lx = i - ly * REGN;
                if (ly < ylo || ly >= yhi || lx < xlo || lx >= xhi)
                    buf[nxt][ly][lx] = NINF;
            }
            __syncthreads();
        }

        // ---- pass 2: op = maxpool(er) at radius 0; delta; skel (registers)
        {
            float a[4], bb[4], c2[4];
            rowmax4(buf[nxt][ly0 - 1], lx0, lx0 - 1, lx0 + 4, a);
            rowmax4(buf[nxt][ly0],     lx0, lx0 - 1, lx0 + 4, bb);
#pragma unroll
            for (int r = 0; r < 4; ++r) {
                rowmax4(buf[nxt][ly0 + r + 1], lx0, lx0 - 1, lx0 + 4, c2);
                float4 ev = *(const float4*)&buf[cur][ly0 + r][lx0];
                float evv[4] = {ev.x, ev.y, ev.z, ev.w};
#pragma unroll
                for (int j = 0; j < 4; ++j) {
                    float op = fmaxf(fmaxf(a[j], bb[j]), c2[j]);
                    float d  = fmaxf(evv[j] - op, 0.0f);
                    if (it == 0) skel[r][j] = d;
                    else         skel[r][j] += fmaxf(d - skel[r][j] * d, 0.0f);
                    a[j] = bb[j]; bb[j] = c2[j];
                }
            }
        }
        __syncthreads();

        // border blocks: er becomes next e -> OOB must be +inf for next min pass
        if (border && it != NITER - 1) {
            for (int i = tid; i < REGN * REGN; i += NTHREADS) {
                int ly = i / REGN, lx = i - ly * REGN;
                if (ly < ylo || ly >= yhi || lx < xlo || lx >= xhi)
                    buf[nxt][ly][lx] = PINF;
            }
            __syncthreads();
        }
        cur = nxt;
    }

    // ---- sums: sp = sum(skel * other), ss = sum(skel)
    float spf = 0.0f, ssf = 0.0f;
    const int gy0 = ty * TILE + rg;
    const int gx0 = tx * TILE + cc;
#pragma unroll
    for (int r = 0; r < 4; ++r) {
        float4 o = *(const float4*)&oth[base + (size_t)(gy0 + r) * IMG + gx0];
        float ov[4] = {o.x, o.y, o.z, o.w};
#pragma unroll
        for (int j = 0; j < 4; ++j) {
            float x = ov[j];
            if (phase) x = 1.0f / (1.0f + __expf(-x));  // pred_prob
            spf += skel[r][j] * x;
            ssf += skel[r][j];
        }
    }
    double sp = (double)spf, ss = (double)ssf;
#pragma unroll
    for (int off = 32; off > 0; off >>= 1) {
        sp += __shfl_down(sp, off);
        ss += __shfl_down(ss, off);
    }
    const int wave = tid >> 6, lane = tid & 63;
    if (lane == 0) { red[wave * 2] = sp; red[wave * 2 + 1] = ss; }
    __syncthreads();
    if (tid == 0) {
        atomicAdd(&ws[phase * 2],     red[0] + red[2] + red[4] + red[6]);
        atomicAdd(&ws[phase * 2 + 1], red[1] + red[3] + red[5] + red[7]);
    }
}

__global__ void cldice_zero(double* __restrict__ ws) {
    if (threadIdx.x < 4) ws[threadIdx.x] = 0.0;
}

__global__ void cldice_final(const double* __restrict__ ws,
                             float* __restrict__ out) {
    if (threadIdx.x == 0 && blockIdx.x == 0) {
        double tprec = (ws[0] + 1.0) / (ws[1] + 1.0);
        double tsens = (ws[2] + 1.0) / (ws[3] + 1.0);
        double cl = 2.0 * tprec * tsens / (tprec + tsens + 1e-7);
        out[0] = (float)(1.0 - cl);
    }
}

extern "C" void kernel_launch(void* const* d_in, const int* in_sizes, int n_in,
                              void* d_out, int out_size, void* d_ws, size_t ws_size,
                              hipStream_t stream) {
    const float* pred   = (const float*)d_in[0];
    const float* target = (const float*)d_in[1];
    double* ws = (double*)d_ws;
    float* out = (float*)d_out;

    cldice_zero<<<dim3(1), dim3(64), 0, stream>>>(ws);
    cldice_main<<<dim3(IMG / TILE, IMG / TILE, 8 * 2), dim3(NTHREADS), 0, stream>>>(
        pred, target, ws);
    cldice_final<<<dim3(1), dim3(64), 0, stream>>>(ws, out);
}

// Round 2
// 344.083 us; speedup vs baseline: 2.0558x; 2.0558x over previous
//
#include <hip/hip_runtime.h>

#define NTHREADS 256
#define TILE 64
#define HALO 12
#define REGN 88      // TILE + 2*HALO
#define STR  92      // padded LDS row stride (floats)
#define NITER 11     // 1 initial + NUM_ITER=10
#define IMG  1024
#define NTILE (IMG / TILE)
#define KROWS 9      // rows per pass-1 job; max jobs = 22*10 = 220 <= 256

// Row 3-min of S[row][x0..x0+3]; left/right neighbors come from the adjacent
// lane's float4 via shfl (conflict-free); edge lanes fall back to a scalar read.
__device__ __forceinline__ void rowmin_s(const float* __restrict__ row,
                                         int x0, int xl, int xr,
                                         bool lv, bool rv, float m[4]) {
    float4 v = *(const float4*)(row + x0);
    float l = __shfl_up(v.w, 1);
    float r = __shfl_down(v.x, 1);
    if (!lv) l = row[xl];
    if (!rv) r = row[xr];
    m[0] = fminf(fminf(l,   v.x), v.y);
    m[1] = fminf(fminf(v.x, v.y), v.z);
    m[2] = fminf(fminf(v.y, v.z), v.w);
    m[3] = fminf(fminf(v.z, v.w), r);
}

__device__ __forceinline__ void rowmax_s(const float* __restrict__ row,
                                         int x0, int xl, int xr,
                                         bool lv, bool rv, float m[4]) {
    float4 v = *(const float4*)(row + x0);
    float l = __shfl_up(v.w, 1);
    float r = __shfl_down(v.x, 1);
    if (!lv) l = row[xl];
    if (!rv) r = row[xr];
    m[0] = fmaxf(fmaxf(l,   v.x), v.y);
    m[1] = fmaxf(fmaxf(v.x, v.y), v.z);
    m[2] = fmaxf(fmaxf(v.y, v.z), v.w);
    m[3] = fmaxf(fmaxf(v.z, v.w), r);
}

// ws[0] = sum(skel_pred * target), ws[1] = sum(skel_pred)
// ws[2] = sum(skel_target * sigmoid(pred)), ws[3] = sum(skel_target)
__global__ __launch_bounds__(NTHREADS, 4)
void cldice_main(const float* __restrict__ pred,
                 const float* __restrict__ target,
                 double* __restrict__ ws)
{
    // single buffer: erode result staged in registers, written back after barrier
    __shared__ __align__(16) float S[REGN][STR];   // 32384 B -> 4 blocks/CU
    __shared__ double red[8];

    const int tid  = threadIdx.x;
    const int lane = tid & 63;
    const int tx = blockIdx.x, ty = blockIdx.y;
    const int b = blockIdx.z >> 1, phase = blockIdx.z & 1;
    const int oy = ty * TILE - HALO;
    const int ox = tx * TILE - HALO;
    const size_t base = (size_t)b * (size_t)(IMG * IMG);
    const float* __restrict__ src = phase ? target : pred;  // img source
    const float* __restrict__ oth = phase ? pred : target;  // multiplied tensor

    const float PINF =  __builtin_huge_valf();
    const float NINF = -__builtin_huge_valf();

    const int ylo = max(0, -oy), yhi = min(REGN, IMG - oy);
    const int xlo = max(0, -ox), xhi = min(REGN, IMG - ox);
    const bool border = (ylo > 0) || (yhi < REGN) || (xlo > 0) || (xhi < REGN);

    // ---- initial load (sigmoid(pred) for phase 0, raw target for 1); OOB = +inf
    for (int i = tid; i < REGN * REGN; i += NTHREADS) {
        int ly = i / REGN, lx = i - ly * REGN;
        int gy = oy + ly, gx = ox + lx;
        float v = PINF;
        if ((unsigned)gy < (unsigned)IMG && (unsigned)gx < (unsigned)IMG) {
            float rr = src[base + (size_t)gy * IMG + gx];
            v = phase ? rr : 1.0f / (1.0f + __expf(-rr));
        }
        S[ly][lx] = v;
    }
    __syncthreads();

    float skel[4][4];
#pragma unroll
    for (int r = 0; r < 4; ++r)
#pragma unroll
        for (int j = 0; j < 4; ++j) skel[r][j] = 0.0f;

    const int rg = (tid >> 4) << 2;   // output row base in tile
    const int cc = (tid & 15) << 2;   // output col base in tile
    const int ly0 = HALO + rg;
    const int lx0 = HALO + cc;
    const bool lv2 = (tid & 15) != 0;
    const bool rv2 = (tid & 15) != 15;

#pragma unroll 1
    for (int it = 0; it < NITER; ++it) {
        const int row0   = it + 1;        // first erode output row
        const int rowEnd = 87 - it;       // exclusive
        const int c0 = row0 >> 2;
        const int c1 = (rowEnd - 1) >> 2;
        const int nch = c1 - c0 + 1;
        const int nrb = (rowEnd - row0 + KROWS - 1) / KROWS;
        const int njobs = nch * nrb;

        const int rb = tid / nch;
        const int ci = tid - rb * nch;
        const int x0 = (c0 + ci) << 2;
        const int r0 = row0 + rb * KROWS;
        const bool act = tid < njobs;
        const bool lv = (ci != 0) && (lane != 0);
        const bool rv = (ci != nch - 1) && (lane != 63);
        const int xl = max(x0 - 1, 0);
        const int xr = min(x0 + 4, REGN - 1);

        // ---- pass 1: erode(S) into registers (uniform trip so shfl is legal)
        float er_[KROWS][4];
        {
            float A[4], B[4];
            rowmin_s(&S[min(r0 - 1, REGN - 1)][0], x0, xl, xr, lv, rv, A);
            rowmin_s(&S[min(r0,     REGN - 1)][0], x0, xl, xr, lv, rv, B);
#pragma unroll
            for (int jj = 0; jj < KROWS; ++jj) {
                float C[4];
                rowmin_s(&S[min(r0 + jj + 1, REGN - 1)][0], x0, xl, xr, lv, rv, C);
#pragma unroll
                for (int j = 0; j < 4; ++j) {
                    er_[jj][j] = fminf(fminf(A[j], B[j]), C[j]);
                    A[j] = B[j]; B[j] = C[j];
                }
            }
        }

        // save e at own patch (needed for delta after S is overwritten)
        float4 ep[4];
#pragma unroll
        for (int r = 0; r < 4; ++r)
            ep[r] = *(const float4*)&S[ly0 + r][lx0];

        __syncthreads();   // all reads of e done

        // ---- write back er (border blocks substitute NINF at image-OOB cells)
        if (act) {
            const bool cv0 = (x0     >= xlo) && (x0     < xhi);
            const bool cv1 = (x0 + 1 >= xlo) && (x0 + 1 < xhi);
            const bool cv2 = (x0 + 2 >= xlo) && (x0 + 2 < xhi);
            const bool cv3 = (x0 + 3 >= xlo) && (x0 + 3 < xhi);
#pragma unroll
            for (int jj = 0; jj < KROWS; ++jj) {
                int r = r0 + jj;
                if (r < rowEnd) {
                    float4 w;
                    w.x = er_[jj][0]; w.y = er_[jj][1];
                    w.z = er_[jj][2]; w.w = er_[jj][3];
                    if (border) {
                        bool rOOB = (r < ylo) || (r >= yhi);
                        w.x = (rOOB || !cv0) ? NINF : w.x;
                        w.y = (rOOB || !cv1) ? NINF : w.y;
                        w.z = (rOOB || !cv2) ? NINF : w.z;
                        w.w = (rOOB || !cv3) ? NINF : w.w;
                    }
                    *(float4*)&S[r][x0] = w;
                }
            }
        }
        __syncthreads();   // er visible

        // ---- pass 2: open = maxpool(er); delta; skel update (all in registers)
        {
            float A[4], B[4];
            rowmax_s(&S[ly0 - 1][0], lx0, lx0 - 1, lx0 + 4, lv2, rv2, A);
            rowmax_s(&S[ly0][0],     lx0, lx0 - 1, lx0 + 4, lv2, rv2, B);
#pragma unroll
            for (int r = 0; r < 4; ++r) {
                float C[4];
                rowmax_s(&S[ly0 + r + 1][0], lx0, lx0 - 1, lx0 + 4, lv2, rv2, C);
                float e4[4] = {ep[r].x, ep[r].y, ep[r].z, ep[r].w};
#pragma unroll
                for (int j = 0; j < 4; ++j) {
                    float op = fmaxf(fmaxf(A[j], B[j]), C[j]);
                    float d  = fmaxf(e4[j] - op, 0.0f);
                    skel[r][j] += fmaxf(d - skel[r][j] * d, 0.0f);
                    A[j] = B[j]; B[j] = C[j];
                }
            }
        }

        // ---- border: restore +inf on OOB cells within next iteration's read range
        if (border && it != NITER - 1) {
            __syncthreads();   // pass-2 reads done
            const int lo = it + 1, hi = 86 - it;   // next pass-1 read range (incl)
            const int NR = hi - lo + 1;
            const int W  = 12 - lo;                // strip width = 11 - it
            if (tx == 0) {
                for (int i = tid; i < W * NR; i += NTHREADS) {
                    int rr = i / W, c2 = i - rr * W;
                    S[lo + rr][lo + c2] = PINF;    // cols [lo, 11]
                }
            }
            if (tx == NTILE - 1) {
                for (int i = tid; i < W * NR; i += NTHREADS) {
                    int rr = i / W, c2 = i - rr * W;
                    S[lo + rr][76 + c2] = PINF;    // cols [76, hi]
                }
            }
            if (ty == 0) {
                for (int i = tid; i < W * NR; i += NTHREADS) {
                    int rr = i / NR, c2 = i - rr * NR;
                    S[lo + rr][lo + c2] = PINF;    // rows [lo, 11]
                }
            }
            if (ty == NTILE - 1) {
                for (int i = tid; i < W * NR; i += NTHREADS) {
                    int rr = i / NR, c2 = i - rr * NR;
                    S[76 + rr][lo + c2] = PINF;    // rows [76, hi]
                }
            }
            __syncthreads();   // PINF visible before next pass-1 reads
        }
    }

    // ---- sums: sp = sum(skel * other), ss = sum(skel)
    float spf = 0.0f, ssf = 0.0f;
    const int gy0 = ty * TILE + rg;
    const int gx0 = tx * TILE + cc;
#pragma unroll
    for (int r = 0; r < 4; ++r) {
        float4 o = *(const float4*)&oth[base + (size_t)(gy0 + r) * IMG + gx0];
        float ov[4] = {o.x, o.y, o.z, o.w};
#pragma unroll
        for (int j = 0; j < 4; ++j) {
            float x = ov[j];
            if (phase) x = 1.0f / (1.0f + __expf(-x));  // pred_prob
            spf += skel[r][j] * x;
            ssf += skel[r][j];
        }
    }
    double sp = (double)spf, ss = (double)ssf;
#pragma unroll
    for (int off = 32; off > 0; off >>= 1) {
        sp += __shfl_down(sp, off);
        ss += __shfl_down(ss, off);
    }
    const int wave = tid >> 6;
    if (lane == 0) { red[wave * 2] = sp; red[wave * 2 + 1] = ss; }
    __syncthreads();
    if (tid == 0) {
        atomicAdd(&ws[phase * 2],     red[0] + red[2] + red[4] + red[6]);
        atomicAdd(&ws[phase * 2 + 1], red[1] + red[3] + red[5] + red[7]);
    }
}

__global__ void cldice_zero(double* __restrict__ ws) {
    if (threadIdx.x < 4) ws[threadIdx.x] = 0.0;
}

__global__ void cldice_final(const double* __restrict__ ws,
                             float* __restrict__ out) {
    if (threadIdx.x == 0 && blockIdx.x == 0) {
        double tprec = (ws[0] + 1.0) / (ws[1] + 1.0);
        double tsens = (ws[2] + 1.0) / (ws[3] + 1.0);
        double cl = 2.0 * tprec * tsens / (tprec + tsens + 1e-7);
        out[0] = (float)(1.0 - cl);
    }
}

extern "C" void kernel_launch(void* const* d_in, const int* in_sizes, int n_in,
                              void* d_out, int out_size, void* d_ws, size_t ws_size,
                              hipStream_t stream) {
    const float* pred   = (const float*)d_in[0];
    const float* target = (const float*)d_in[1];
    double* ws = (double*)d_ws;
    float* out = (float*)d_out;

    cldice_zero<<<dim3(1), dim3(64), 0, stream>>>(ws);
    cldice_main<<<dim3(NTILE, NTILE, 8 * 2), dim3(NTHREADS), 0, stream>>>(
        pred, target, ws);
    cldice_final<<<dim3(1), dim3(64), 0, stream>>>(ws, out);
}